// Round 5
// baseline (110.632 us; speedup 1.0000x reference)
//
#include <hip/hip_runtime.h>
#include <hip/hip_bf16.h>
#include <math.h>

// Decoder: h = relu(cat @ W_h + b_h); t = selu(h @ W1 + b1);
// x = sigmoid(t @ W2 + b2); loss = sum_w(softplus(z) - z*img)   [== -(BCE log-lik)]
// R = S*B = 4096 rows; Hn=512, bott=160, P=12288 = 192 groups * 64 (w).

#define SELU_SCALE 1.0507009873554804934193349852946f
#define SELU_ALPHA 1.6732632423543772848170429916717f

typedef __attribute__((ext_vector_type(8))) short bf16x8;   // 8 bf16 (4 VGPRs)
typedef __attribute__((ext_vector_type(4))) float f32x4;    // MFMA accumulator

// ---------------- K0: W2T[n][k] = bf16(W2[k][n]) ---------------------------
__global__ __launch_bounds__(256) void w2_transpose_kernel(
    const float* __restrict__ W2,        // [160,12288]
    __hip_bfloat16* __restrict__ W2T)    // [12288,160]
{
    __shared__ float tile[32][33];
    const int nBase = blockIdx.x * 32;
    const int kBase = blockIdx.y * 32;
    const int tx = threadIdx.x & 31;
    const int ty = threadIdx.x >> 5;     // 0..7
#pragma unroll
    for (int i = 0; i < 4; ++i) {
        const int k = kBase + ty + i * 8;
        tile[ty + i * 8][tx] = W2[(size_t)k * 12288 + nBase + tx];
    }
    __syncthreads();
#pragma unroll
    for (int i = 0; i < 4; ++i) {
        const int n = nBase + ty + i * 8;
        W2T[(size_t)n * 160 + kBase + tx] = __float2bfloat16(tile[tx][ty + i * 8]);
    }
}

// ---------------- K1: h[R,512] = bf16(relu(cat @ Wh + bh)) -----------------
__global__ __launch_bounds__(512) void dec_hidden_kernel(
    const float* __restrict__ digits,   // [R,10]
    const float* __restrict__ styles,   // [R,50]
    const float* __restrict__ Wh,       // [60,512]
    const float* __restrict__ bh,       // [512]
    __hip_bfloat16* __restrict__ h)     // [R,512] bf16
{
    __shared__ float cat_s[8][60];
    const int tid = threadIdx.x;
    const int rowBase = blockIdx.x * 8;

    for (int i = tid; i < 8 * 60; i += 512) {
        const int r = i / 60, k = i % 60;
        const int row = rowBase + r;
        cat_s[r][k] = (k < 10) ? digits[row * 10 + k]
                               : styles[row * 50 + (k - 10)];
    }
    __syncthreads();

    float acc[8];
    const float bias = bh[tid];
#pragma unroll
    for (int r = 0; r < 8; ++r) acc[r] = bias;

    for (int k = 0; k < 60; ++k) {
        const float w = Wh[k * 512 + tid];
#pragma unroll
        for (int r = 0; r < 8; ++r) acc[r] = fmaf(cat_s[r][k], w, acc[r]);
    }
#pragma unroll
    for (int r = 0; r < 8; ++r)
        h[(size_t)(rowBase + r) * 512 + tid] = __float2bfloat16(fmaxf(acc[r], 0.0f));
}

// ---------------- K2: t[R,160] = bf16(selu(h @ W1 + b1)) -------------------
__global__ __launch_bounds__(192) void hidden1_kernel(
    const __hip_bfloat16* __restrict__ h,   // [R,512] bf16
    const float* __restrict__ W1,           // [512,160]
    const float* __restrict__ b1,           // [160]
    __hip_bfloat16* __restrict__ t)         // [R,160] bf16
{
    __shared__ float h_s[8 * 512];
    const int tid = threadIdx.x;
    const int rowBase = blockIdx.x * 8;
    const __hip_bfloat16* hsrc = h + (size_t)rowBase * 512;
    for (int i = tid; i < 8 * 512; i += 192) h_s[i] = __bfloat162float(hsrc[i]);
    __syncthreads();

    if (tid < 160) {
        float acc[8];
        const float bias = b1[tid];
#pragma unroll
        for (int r = 0; r < 8; ++r) acc[r] = bias;

        for (int k = 0; k < 512; k += 4) {
            const float w0 = W1[(size_t)(k + 0) * 160 + tid];
            const float w1 = W1[(size_t)(k + 1) * 160 + tid];
            const float w2 = W1[(size_t)(k + 2) * 160 + tid];
            const float w3 = W1[(size_t)(k + 3) * 160 + tid];
#pragma unroll
            for (int r = 0; r < 8; ++r) {
                const float4 hv = *(const float4*)&h_s[r * 512 + k];
                float a = acc[r];
                a = fmaf(hv.x, w0, a);
                a = fmaf(hv.y, w1, a);
                a = fmaf(hv.z, w2, a);
                a = fmaf(hv.w, w3, a);
                acc[r] = a;
            }
        }
#pragma unroll
        for (int r = 0; r < 8; ++r) {
            const float z = acc[r];
            const float s = (z > 0.0f) ? (SELU_SCALE * z)
                                       : (SELU_SCALE * SELU_ALPHA * expm1f(z));
            t[(size_t)(rowBase + r) * 160 + tid] = __float2bfloat16(s);
        }
    }
}

// ---------------- K3: MFMA GEMM (t @ W2) fused with sigmoid-BCE loss -------
// grid (96, 32); block 256 = 4 waves as 2x2; block tile 128x128, wave 64x64.
// SWAPPED operands: acc[cw][rw] = mfma(w2_frag[cw], t_frag[rw], ...) computes
// z^T, so each lane owns ONE t-row (lane&15) and CONSECUTIVE col quads
// ((lane>>4)*4+j) -> images load as float4, one v_log_f32 per 16 elements,
// w-reduce = 2 shuffles. Image batches rw={0,1} issued under the GEMM,
// {2,3} under the rw=0/1 epilogue.
__global__ __launch_bounds__(256) void out_loss_mfma_kernel(
    const __hip_bfloat16* __restrict__ t,    // [4096,160]
    const __hip_bfloat16* __restrict__ w2t,  // [12288,160]
    const float* __restrict__ b2,            // [12288]
    const float* __restrict__ images,        // [4096,12288]
    float* __restrict__ out)                 // [4096,192]
{
    const int tid = threadIdx.x;
    const int lane = tid & 63;
    const int wv = tid >> 6;
    const int wm = wv >> 1, wn = wv & 1;
    const int rowBase = blockIdx.y * 128 + wm * 64;   // t rows
    const int colBase = blockIdx.x * 128 + wn * 64;   // w2 cols
    const int lr = lane & 15;     // t-row within 16-frag / w2-col within frag
    const int lh = lane >> 4;     // k-subblock on load; col-quad on output

    const short* tb = (const short*)t;
    const short* wb = (const short*)w2t;

    // fragment loads for kk = 0
    bf16x8 aW[4], bT[4];
#pragma unroll
    for (int c = 0; c < 4; ++c)
        aW[c] = *(const bf16x8*)(wb + (size_t)(colBase + c * 16 + lr) * 160 + lh * 8);
#pragma unroll
    for (int r = 0; r < 4; ++r)
        bT[r] = *(const bf16x8*)(tb + (size_t)(rowBase + r * 16 + lr) * 160 + lh * 8);

    // image batches rw = 0,1 (float4, 16B/lane) — latency hides under GEMM
    const float* imgB = images + colBase + lh * 4;    // + row*12288 + cw*16
    float4 img[4][4];
#pragma unroll
    for (int rw = 0; rw < 2; ++rw)
#pragma unroll
        for (int c = 0; c < 4; ++c)
            img[rw][c] = *(const float4*)(imgB
                + (size_t)(rowBase + rw * 16 + lr) * 12288 + c * 16);

    f32x4 acc[4][4] = {};   // [cw][rw]

    // kk = 0 MFMAs
#pragma unroll
    for (int c = 0; c < 4; ++c)
#pragma unroll
        for (int r = 0; r < 4; ++r)
            acc[c][r] = __builtin_amdgcn_mfma_f32_16x16x32_bf16(
                aW[c], bT[r], acc[c][r], 0, 0, 0);

    // kk = 1..4
#pragma unroll
    for (int kk = 1; kk < 5; ++kk) {
#pragma unroll
        for (int c = 0; c < 4; ++c)
            aW[c] = *(const bf16x8*)(wb + (size_t)(colBase + c * 16 + lr) * 160
                                        + kk * 32 + lh * 8);
#pragma unroll
        for (int r = 0; r < 4; ++r)
            bT[r] = *(const bf16x8*)(tb + (size_t)(rowBase + r * 16 + lr) * 160
                                        + kk * 32 + lh * 8);
#pragma unroll
        for (int c = 0; c < 4; ++c)
#pragma unroll
            for (int r = 0; r < 4; ++r)
                acc[c][r] = __builtin_amdgcn_mfma_f32_16x16x32_bf16(
                    aW[c], bT[r], acc[c][r], 0, 0, 0);
    }

    // image batches rw = 2,3 — latency hides under rw=0/1 epilogue
#pragma unroll
    for (int rw = 2; rw < 4; ++rw)
#pragma unroll
        for (int c = 0; c < 4; ++c)
            img[rw][c] = *(const float4*)(imgB
                + (size_t)(rowBase + rw * 16 + lr) * 12288 + c * 16);

    // bias quads (L2-hot)
    float4 bc[4];
#pragma unroll
    for (int c = 0; c < 4; ++c)
        bc[c] = *(const float4*)(b2 + colBase + c * 16 + lh * 4);

    const int group = blockIdx.x * 2 + wn;    // w-group = 64-col slab
#pragma unroll
    for (int rw = 0; rw < 4; ++rw) {
        float mx = 0.f;   // Σ max(z,0)
        float pr = 1.f;   // Π (1+e^{-|z|})   (16 terms, ≤ 2^16: fp32-safe)
        float zi = 0.f;   // Σ z*im
#pragma unroll
        for (int c = 0; c < 4; ++c) {
            const float4 im4 = img[rw][c];
            const float imv[4] = {im4.x, im4.y, im4.z, im4.w};
            const float bcv[4] = {bc[c].x, bc[c].y, bc[c].z, bc[c].w};
#pragma unroll
            for (int j = 0; j < 4; ++j) {
                const float z = acc[c][rw][j] + bcv[j];
                mx += fmaxf(z, 0.0f);
                pr *= 1.0f + __expf(-fabsf(z));   // native v_exp_f32
                zi = fmaf(z, imv[j], zi);
            }
        }
        float part = mx + __logf(pr) - zi;        // native v_log_f32

        // reduce over the 4 lh groups (each holds 16 of the 64 w-cols)
        part += __shfl_xor(part, 16);
        part += __shfl_xor(part, 32);

        if (lane < 16)
            out[(size_t)(rowBase + rw * 16 + lr) * 192 + group] = part;
    }
}

extern "C" void kernel_launch(void* const* d_in, const int* in_sizes, int n_in,
                              void* d_out, int out_size, void* d_ws, size_t ws_size,
                              hipStream_t stream) {
    const float* digits = (const float*)d_in[0];  // [8,512,10]
    const float* styles = (const float*)d_in[1];  // [8,512,50]
    const float* images = (const float*)d_in[2];  // [8,512,3,64,64]
    const float* Wh     = (const float*)d_in[3];  // [60,512]
    const float* bh     = (const float*)d_in[4];  // [512]
    const float* W1     = (const float*)d_in[5];  // [512,160]
    const float* b1     = (const float*)d_in[6];  // [160]
    const float* W2     = (const float*)d_in[7];  // [160,12288]
    const float* b2     = (const float*)d_in[8];  // [12288]
    float* out = (float*)d_out;                   // [4096,192]

    const int R = 4096;

    // workspace (9 MB total): h bf16 [R,512] | t bf16 [R,160] | W2T bf16 [12288,160]
    __hip_bfloat16* h   = (__hip_bfloat16*)d_ws;
    __hip_bfloat16* tt  = h + (size_t)R * 512;
    __hip_bfloat16* w2t = tt + (size_t)R * 160;

    dim3 gridT(384, 5);
    w2_transpose_kernel<<<gridT, 256, 0, stream>>>(W2, w2t);

    dec_hidden_kernel<<<R / 8, 512, 0, stream>>>(digits, styles, Wh, bh, h);
    hidden1_kernel<<<R / 8, 192, 0, stream>>>(h, W1, b1, tt);

    dim3 grid3(96, 32);
    out_loss_mfma_kernel<<<grid3, 256, 0, stream>>>(tt, w2t, b2, images, out);
}